// Round 8
// baseline (1270.273 us; speedup 1.0000x reference)
//
#include <hip/hip_runtime.h>
#include <hip/hip_bf16.h>

typedef unsigned short u16;
typedef unsigned long long u64;
typedef __attribute__((ext_vector_type(8))) short short8;
typedef __attribute__((ext_vector_type(4))) float f32x4;
typedef __attribute__((ext_vector_type(2))) float f32x2;

#define NN 8192
#define SSAMP 1024
#define KK 32
#define NT_F 524288.0f
#define EPSV 1e-5f

__device__ __forceinline__ u64 umax64(u64 a, u64 b) { return a > b ? a : b; }

template <int C>
__device__ __forceinline__ void dppstep(unsigned& hi, unsigned& lo) {
  unsigned h2 = (unsigned)__builtin_amdgcn_update_dpp(0, (int)hi, C, 0xF, 0xF, true);
  unsigned l2 = (unsigned)__builtin_amdgcn_update_dpp(0, (int)lo, C, 0xF, 0xF, true);
  u64 a = ((u64)hi << 32) | lo;
  u64 b = ((u64)h2 << 32) | l2;
  bool g = b > a;
  hi = g ? h2 : hi;
  lo = g ? l2 : lo;
}

// Full wave64 u64 max-reduce; valid result in lane 63 (rare tie fallback).
__device__ __forceinline__ u64 wave_max_key(u64 key) {
  unsigned hi = (unsigned)(key >> 32), lo = (unsigned)key;
  dppstep<0x111>(hi, lo);
  dppstep<0x112>(hi, lo);
  dppstep<0x114>(hi, lo);
  dppstep<0x118>(hi, lo);
  dppstep<0x142>(hi, lo);
  dppstep<0x143>(hi, lo);
  return ((u64)hi << 32) | lo;
}

// f32 max DPP step (fusable into v_max_f32_dpp). Fill 0 can't win: operands>=0
// and the true max is >0.
template <int C>
__device__ __forceinline__ float maxdpp(float v) {
  float o = __int_as_float(__builtin_amdgcn_update_dpp(0, __float_as_int(v), C, 0xF, 0xF, true));
  return fmaxf(v, o);
}

__device__ __forceinline__ u64 rl64(u64 v, int lane) {
  unsigned lo = (unsigned)__builtin_amdgcn_readlane((int)(unsigned)v, lane);
  unsigned hi = (unsigned)__builtin_amdgcn_readlane((int)(unsigned)(v >> 32), lane);
  return ((u64)hi << 32) | lo;
}

__device__ __forceinline__ int morton3(int ix, int iy, int iz) {
  int m = (((ix >> 0) & 1) << 2) | (((iy >> 0) & 1) << 1) | (((iz >> 0) & 1) << 0);
  m |= (((ix >> 1) & 1) << 5) | (((iy >> 1) & 1) << 4) | (((iz >> 1) & 1) << 3);
  m |= (((ix >> 2) & 1) << 8) | (((iy >> 2) & 1) << 7) | (((iz >> 2) & 1) << 6);
  return m;
}

// ---------------------------------------------------------------------------
// FPS v8: bucketed + pruned; packed-f32 (v_pk) distance update with
// fp contract(off) (bit-exact vs reference mul/add chain); post-hoc argmax
// index recovery; cheap f32-DPP wave reduce + single-match readlane of the
// winner's cached key (u64 DPP only on exact float ties). Cross-wave combine
// via 4 LDS atomicMax slots, 3-buffer rotation, 1 barrier/iter.
// ---------------------------------------------------------------------------
__global__ __launch_bounds__(1024, 1) void fps_bucket_kernel(const float* __restrict__ xyz,
                                                             float* __restrict__ newxyz) {
  extern __shared__ float4 sp4[];  // [NN]: x,y,z, bitcast(orig idx)
  __shared__ int cnt[512], off[512];
  __shared__ __align__(32) u64 candS[3][4];
  __shared__ int pos0_sh;

  const int b = blockIdx.x, t = threadIdx.x;
  const float* base = xyz + (size_t)b * NN * 3;

  float px[8], py[8], pz[8];
  int pc[8];
  if (t < 512) cnt[t] = 0;
  if (t < 12) candS[t >> 2][t & 3] = 0;
  __syncthreads();
#pragma unroll
  for (int j = 0; j < 8; j++) {
    int p = j * 1024 + t;
    px[j] = base[p * 3 + 0];
    py[j] = base[p * 3 + 1];
    pz[j] = base[p * 3 + 2];
    int ix = min(7, (int)(px[j] * 8.0f));
    int iy = min(7, (int)(py[j] * 8.0f));
    int iz = min(7, (int)(pz[j] * 8.0f));
    pc[j] = morton3(ix, iy, iz);
    atomicAdd(&cnt[pc[j]], 1);
  }
  __syncthreads();
  int myc = (t < 512) ? cnt[t] : 0;
  for (int st = 1; st < 512; st <<= 1) {
    int v = 0;
    if (t < 512) { v = cnt[t]; if (t >= st) v += cnt[t - st]; }
    __syncthreads();
    if (t < 512) cnt[t] = v;
    __syncthreads();
  }
  if (t < 512) off[t] = cnt[t] - myc;
  __syncthreads();
#pragma unroll
  for (int j = 0; j < 8; j++) {
    int pos = atomicAdd(&off[pc[j]], 1);
    int orig = j * 1024 + t;
    sp4[pos] = make_float4(px[j], py[j], pz[j], __int_as_float(orig));
    if (orig == 0) pos0_sh = pos;
  }
  __syncthreads();
  f32x2 X2[4], Y2[4], Z2[4], D2[4];
  unsigned L26[8];
  float lox = 1e30f, loy = 1e30f, loz = 1e30f;
  float hix = -1e30f, hiy = -1e30f, hiz = -1e30f;
#pragma unroll
  for (int j = 0; j < 8; j++) {
    int p = t * 8 + j;
    float4 v = sp4[p];
    X2[j >> 1][j & 1] = v.x; Y2[j >> 1][j & 1] = v.y; Z2[j >> 1][j & 1] = v.z;
    D2[j >> 1][j & 1] = 1e10f;
    int orig = __float_as_int(v.w);
    L26[j] = ((unsigned)(8191 - orig) << 13) | (unsigned)p;
    lox = fminf(lox, v.x); hix = fmaxf(hix, v.x);
    loy = fminf(loy, v.y); hiy = fmaxf(hiy, v.y);
    loz = fminf(loz, v.z); hiz = fmaxf(hiz, v.z);
  }
  int cur = pos0_sh;
  const int w = t >> 6, sl = w & 3, lane = t & 63;
  u64 ckey = 0;
  float cbd = 1e10f;
  int s = 0;

  for (int it = 0; it < SSAMP; it++) {
    const int sn = (s == 2) ? 0 : s + 1;
    float4 c4 = sp4[cur];
    float cx = c4.x, cy = c4.y, cz = c4.z;
    if (t == 0) {
      float* o = newxyz + ((size_t)b * SSAMP + it) * 3;
      o[0] = cx; o[1] = cy; o[2] = cz;
    }
    float ddx = fmaxf(fmaxf(lox - cx, cx - hix), 0.f);
    float ddy = fmaxf(fmaxf(loy - cy, cy - hiy), 0.f);
    float ddz = fmaxf(fmaxf(loz - cz, cz - hiz), 0.f);
    float lb2 = fmaf(ddx, ddx, fmaf(ddy, ddy, ddz * ddz));
    bool upd = lb2 <= fmaf(cbd, 1.0001f, 1e-12f);
    if (upd) {
#pragma clang fp contract(off)
      f32x2 cxx, cyy, czz, bdv;
      cxx[0] = cx; cxx[1] = cx;
      cyy[0] = cy; cyy[1] = cy;
      czz[0] = cz; czz[1] = cz;
      bdv[0] = -1.f; bdv[1] = -1.f;
#pragma unroll
      for (int j2 = 0; j2 < 4; j2++) {
        f32x2 dx = X2[j2] - cxx;
        f32x2 dy = Y2[j2] - cyy;
        f32x2 dz = Z2[j2] - czz;
        f32x2 d = (dx * dx + dy * dy) + dz * dz;
        f32x2 dm = __builtin_elementwise_min(D2[j2], d);
        D2[j2] = dm;
        bdv = __builtin_elementwise_max(bdv, dm);
      }
      float bd = fmaxf(bdv[0], bdv[1]);
      u64 k = 0;
#pragma unroll
      for (int j = 0; j < 8; j++) {
        float dmj = D2[j >> 1][j & 1];
        u64 kj = ((u64)__float_as_uint(dmj) << 26) | (u64)L26[j];
        k = (dmj == bd) ? umax64(k, kj) : k;
      }
      ckey = k;
      cbd = bd;
    }
    // cheap wave reduce on cbd (always)
    float wmp = cbd;
    wmp = maxdpp<0x111>(wmp);
    wmp = maxdpp<0x112>(wmp);
    wmp = maxdpp<0x114>(wmp);
    wmp = maxdpp<0x118>(wmp);
    wmp = maxdpp<0x142>(wmp);
    wmp = maxdpp<0x143>(wmp);
    float wm = __int_as_float(__builtin_amdgcn_readlane(__float_as_int(wmp), 63));
    u64 mask = __ballot(cbd == wm);
    u64 wkey;
    if (__popcll(mask) == 1) {
      wkey = rl64(ckey, (int)(__ffsll((long long)mask) - 1));
    } else {
      wkey = rl64(wave_max_key(ckey), 63);  // exact tie: full u64 reduce
    }
    if (lane == 63) atomicMax(&candS[s][sl], wkey);
    if (t < 4) candS[sn][t] = 0;  // race-free per 3-buffer rotation
    __syncthreads();
    u64 m0 = umax64(candS[s][0], candS[s][1]);
    u64 m1 = umax64(candS[s][2], candS[s][3]);
    cur = (int)(umax64(m0, m1) & 0x1FFFull);
    s = sn;
  }
}

// ---------------------------------------------------------------------------
// FPS fallback (global loads) if big-LDS launch isn't grantable.
// ---------------------------------------------------------------------------
__global__ __launch_bounds__(512, 1) void fps_fallback_kernel(const float* __restrict__ xyz,
                                                              float* __restrict__ newxyz) {
  const int b = blockIdx.x, t = threadIdx.x;
  const float* base = xyz + (size_t)b * NN * 3;
  __shared__ u64 cand[2][8];
  float X[16], Y[16], Z[16], D[16];
#pragma unroll
  for (int j = 0; j < 16; j++) {
    int p = j * 512 + t;
    X[j] = base[p * 3 + 0];
    Y[j] = base[p * 3 + 1];
    Z[j] = base[p * 3 + 2];
    D[j] = 1e10f;
  }
  __syncthreads();
  int cur = 0;
  const int w = t >> 6;
  for (int it = 0; it < SSAMP; it++) {
    float cx = base[cur * 3 + 0];
    float cy = base[cur * 3 + 1];
    float cz = base[cur * 3 + 2];
    if (t == 0) {
      float* o = newxyz + ((size_t)b * SSAMP + it) * 3;
      o[0] = cx; o[1] = cy; o[2] = cz;
    }
    float bestd = -1.0f;
    int bj = 0;
#pragma unroll
    for (int j = 0; j < 16; j++) {
      float dx = __fsub_rn(X[j], cx);
      float dy = __fsub_rn(Y[j], cy);
      float dz = __fsub_rn(Z[j], cz);
      float d = __fadd_rn(__fadd_rn(__fmul_rn(dx, dx), __fmul_rn(dy, dy)), __fmul_rn(dz, dz));
      float dm = fminf(D[j], d);
      D[j] = dm;
      bool g = dm > bestd;
      bestd = g ? dm : bestd;
      bj = g ? j : bj;
    }
    u64 key = ((u64)__float_as_uint(bestd) << 32) |
              (u64)(unsigned)~(unsigned)(bj * 512 + t);
    key = wave_max_key(key);
    const int s = it & 1;
    if ((t & 63) == 63) cand[s][w] = key;
    __syncthreads();
    u64 c0 = cand[s][0], c1 = cand[s][1], c2 = cand[s][2], c3 = cand[s][3];
    u64 c4 = cand[s][4], c5 = cand[s][5], c6 = cand[s][6], c7 = cand[s][7];
    u64 a0 = umax64(c0, c1), a1 = umax64(c2, c3), a2 = umax64(c4, c5), a3 = umax64(c6, c7);
    u64 best = umax64(umax64(a0, a1), umax64(a2, a3));
    cur = (int)(~(unsigned)(best & 0xFFFFFFFFull));
  }
}

// ---------------------------------------------------------------------------
// Ball query: one WAVE per centroid, 64-pt chunks, ballot + rank compaction.
// ---------------------------------------------------------------------------
__global__ __launch_bounds__(256) void ballq_kernel(const float* __restrict__ xyz,
                                                    const float* __restrict__ newxyz,
                                                    int* __restrict__ ballidx) {
  const int wid = blockIdx.x * 4 + (threadIdx.x >> 6);
  const int lane = threadIdx.x & 63;
  const int b = wid >> 10;
  const float* base = xyz + (size_t)b * NN * 3;
  const float cx = newxyz[wid * 3 + 0];
  const float cy = newxyz[wid * 3 + 1];
  const float cz = newxyz[wid * 3 + 2];
  int* op = ballidx + (size_t)wid * KK;
  int cnt = 0, first = -1;
  for (int p0 = 0; p0 < NN; p0 += 64) {
    const int p = p0 + lane;
    float dx = __fsub_rn(cx, base[p * 3 + 0]);
    float dy = __fsub_rn(cy, base[p * 3 + 1]);
    float dz = __fsub_rn(cz, base[p * 3 + 2]);
    float d = __fadd_rn(__fadd_rn(__fmul_rn(dx, dx), __fmul_rn(dy, dy)), __fmul_rn(dz, dz));
    bool hit = d <= 0.04f;
    u64 m = __ballot(hit);
    if (m) {
      if (first < 0) first = p0 + __ffsll((long long)m) - 1;
      int rank = __popcll(m & ((1ull << lane) - 1ull));
      int slot = cnt + rank;
      if (hit && slot < KK) op[slot] = p;
      cnt += __popcll(m);
      if (cnt >= KK) break;
    }
  }
  if (cnt < KK && lane >= cnt && lane < KK) op[lane] = first;
}

__global__ __launch_bounds__(256) void collapse_kernel(const float* __restrict__ bkt,
                                                       float* __restrict__ dst) {
  int e = blockIdx.x * 256 + threadIdx.x;
  float s = 0.f;
#pragma unroll 8
  for (int u = 0; u < 64; u++) s += bkt[u * 512 + e];
  dst[e] = s;
}

// pack helpers (packed bf16 converts)
__device__ __forceinline__ void put2(short8& r, int x, float f0, float f1) {
  __hip_bfloat162 p = __float22bfloat162_rn(make_float2(f0, f1));
  unsigned u = *(const unsigned*)&p;
  r[x] = (short)(u16)(u & 0xFFFF);
  r[x + 1] = (short)(u16)(u >> 16);
}

__device__ __forceinline__ short8 bn_pack8(const u16 h[8], const float* sS, const float* sT, int c0) {
  short8 r;
#pragma unroll
  for (int x = 0; x < 8; x += 2) {
    float f0 = __bfloat162float(*(const __hip_bfloat16*)&h[x]);
    float f1 = __bfloat162float(*(const __hip_bfloat16*)&h[x + 1]);
    f0 = fmaxf(fmaf(f0, sS[c0 + x], sT[c0 + x]), 0.f);
    f1 = fmaxf(fmaf(f1, sS[c0 + x + 1], sT[c0 + x + 1]), 0.f);
    put2(r, x, f0, f1);
  }
  return r;
}

__device__ __forceinline__ short8 w_pack8(const float v[8]) {
  short8 r;
#pragma unroll
  for (int x = 0; x < 8; x += 2) put2(r, x, v[x], v[x + 1]);
  return r;
}

// ---------------------------------------------------------------------------
// GEMM1 (MFMA bf16): gather(points, xyz_norm) -> conv1(67->64)+bias, Y bf16.
// K reorder: k0..63 = point ch 3..66, k64..66 = xyz_norm, rest zero.
// ---------------------------------------------------------------------------
__global__ __launch_bounds__(256) void gemm1_mfma_kernel(const float* __restrict__ xyz,
                                                         const float* __restrict__ pts,
                                                         const float* __restrict__ w1,
                                                         const float* __restrict__ b1,
                                                         const float* __restrict__ newxyz,
                                                         const int* __restrict__ ballidx,
                                                         u16* __restrict__ Y,
                                                         float* __restrict__ bkt) {
  __shared__ __align__(16) short Af[12 * 64 * 8];
  __shared__ __align__(16) short Bf[12 * 64 * 8];
  __shared__ __align__(16) u16 Cs[64 * 72];
  __shared__ int sidx[64];
  __shared__ float snx[6];
  __shared__ float sSum[64], sSq[64];
  const int t = threadIdx.x, blk = blockIdx.x;
  const int pbase = blk * 64;
  const int g0 = pbase >> 5;
  const int b = g0 >> 10;
  if (t < 64) sidx[t] = ballidx[pbase + t];
  if (t < 6) snx[t] = newxyz[(size_t)g0 * 3 + t];
  __syncthreads();
  {
    int r = t >> 2, q = t & 3;
    const float4* prow = (const float4*)(pts + ((size_t)b * NN + sidx[r]) * 64);
    float4 v0 = prow[q * 4 + 0], v1 = prow[q * 4 + 1];
    float4 v2 = prow[q * 4 + 2], v3 = prow[q * 4 + 3];
    float f0[8] = {v0.x, v0.y, v0.z, v0.w, v1.x, v1.y, v1.z, v1.w};
    float f1[8] = {v2.x, v2.y, v2.z, v2.w, v3.x, v3.y, v3.z, v3.w};
    int kt = q >> 1, mt = r >> 4, m = r & 15;
    int qp0 = (2 * q) & 3, qp1 = (2 * q + 1) & 3;
    *(short8*)&Af[((mt * 3 + kt) * 64 + qp0 * 16 + m) * 8] = w_pack8(f0);
    *(short8*)&Af[((mt * 3 + kt) * 64 + qp1 * 16 + m) * 8] = w_pack8(f1);
  }
  {
    int o = t >> 2, q = t & 3;
    const float* wr = w1 + o * 67 + 3 + q * 16;
    float f0[8], f1[8];
#pragma unroll
    for (int x = 0; x < 8; x++) { f0[x] = wr[x]; f1[x] = wr[8 + x]; }
    int kt = q >> 1, nt = o >> 4, n = o & 15;
    int qp0 = (2 * q) & 3, qp1 = (2 * q + 1) & 3;
    *(short8*)&Bf[((nt * 3 + kt) * 64 + qp0 * 16 + n) * 8] = w_pack8(f0);
    *(short8*)&Bf[((nt * 3 + kt) * 64 + qp1 * 16 + n) * 8] = w_pack8(f1);
  }
  if (t < 64) {
    const float* xp = xyz + ((size_t)b * NN + sidx[t]) * 3;
    int g = t >> 5, mt = t >> 4, m = t & 15;
    float xn = xp[0] - snx[g * 3 + 0];
    float yn = xp[1] - snx[g * 3 + 1];
    float zn = xp[2] - snx[g * 3 + 2];
    short8 s0 = {0, 0, 0, 0, 0, 0, 0, 0};
    short8 z8 = {0, 0, 0, 0, 0, 0, 0, 0};
    __hip_bfloat16 hb;
    hb = __float2bfloat16(xn); s0[0] = *(const short*)&hb;
    hb = __float2bfloat16(yn); s0[1] = *(const short*)&hb;
    hb = __float2bfloat16(zn); s0[2] = *(const short*)&hb;
    *(short8*)&Af[((mt * 3 + 2) * 64 + 0 * 16 + m) * 8] = s0;
    *(short8*)&Af[((mt * 3 + 2) * 64 + 1 * 16 + m) * 8] = z8;
    *(short8*)&Af[((mt * 3 + 2) * 64 + 2 * 16 + m) * 8] = z8;
    *(short8*)&Af[((mt * 3 + 2) * 64 + 3 * 16 + m) * 8] = z8;
  } else if (t < 128) {
    int o = t - 64, nt = o >> 4, n = o & 15;
    short8 s0 = {0, 0, 0, 0, 0, 0, 0, 0};
    short8 z8 = {0, 0, 0, 0, 0, 0, 0, 0};
    __hip_bfloat16 hb;
    hb = __float2bfloat16(w1[o * 67 + 0]); s0[0] = *(const short*)&hb;
    hb = __float2bfloat16(w1[o * 67 + 1]); s0[1] = *(const short*)&hb;
    hb = __float2bfloat16(w1[o * 67 + 2]); s0[2] = *(const short*)&hb;
    *(short8*)&Bf[((nt * 3 + 2) * 64 + 0 * 16 + n) * 8] = s0;
    *(short8*)&Bf[((nt * 3 + 2) * 64 + 1 * 16 + n) * 8] = z8;
    *(short8*)&Bf[((nt * 3 + 2) * 64 + 2 * 16 + n) * 8] = z8;
    *(short8*)&Bf[((nt * 3 + 2) * 64 + 3 * 16 + n) * 8] = z8;
  }
  __syncthreads();
  const int w = t >> 6, L = t & 63, q = L >> 4;
  const int nt = w;
  short8 b0 = *(const short8*)&Bf[((nt * 3 + 0) * 64 + L) * 8];
  short8 b1v = *(const short8*)&Bf[((nt * 3 + 1) * 64 + L) * 8];
  short8 b2v = *(const short8*)&Bf[((nt * 3 + 2) * 64 + L) * 8];
  const int o = nt * 16 + (L & 15);
  const float bl = b1[o];
  f32x4 acc[4];
#pragma unroll
  for (int mt = 0; mt < 4; mt++) {
    acc[mt] = (f32x4){0.f, 0.f, 0.f, 0.f};
    short8 a0 = *(const short8*)&Af[((mt * 3 + 0) * 64 + L) * 8];
    short8 a1 = *(const short8*)&Af[((mt * 3 + 1) * 64 + L) * 8];
    short8 a2 = *(const short8*)&Af[((mt * 3 + 2) * 64 + L) * 8];
    acc[mt] = __builtin_amdgcn_mfma_f32_16x16x32_bf16(a0, b0, acc[mt], 0, 0, 0);
    acc[mt] = __builtin_amdgcn_mfma_f32_16x16x32_bf16(a1, b1v, acc[mt], 0, 0, 0);
    acc[mt] = __builtin_amdgcn_mfma_f32_16x16x32_bf16(a2, b2v, acc[mt], 0, 0, 0);
  }
  float s = 0.f, q2 = 0.f;
#pragma unroll
  for (int mt = 0; mt < 4; mt++) {
    float yv[4];
#pragma unroll
    for (int r = 0; r < 4; r++) {
      yv[r] = acc[mt][r] + bl;
      s += yv[r]; q2 += yv[r] * yv[r];
    }
#pragma unroll
    for (int r = 0; r < 4; r += 2) {
      __hip_bfloat162 p = __float22bfloat162_rn(make_float2(yv[r], yv[r + 1]));
      unsigned u = *(const unsigned*)&p;
      Cs[(mt * 16 + q * 4 + r) * 72 + o] = (u16)(u & 0xFFFF);
      Cs[(mt * 16 + q * 4 + r + 1) * 72 + o] = (u16)(u >> 16);
    }
  }
  s += __shfl_xor(s, 16); s += __shfl_xor(s, 32);
  q2 += __shfl_xor(q2, 16); q2 += __shfl_xor(q2, 32);
  if (L < 16) { sSum[o] = s; sSq[o] = q2; }
  __syncthreads();
  {
    int r = t >> 2, qq = t & 3;
    uint4 c0 = *(const uint4*)&Cs[r * 72 + qq * 16];
    uint4 c1 = *(const uint4*)&Cs[r * 72 + qq * 16 + 8];
    uint4* yrow = (uint4*)(Y + (size_t)(pbase + r) * 64);
    yrow[qq * 2] = c0; yrow[qq * 2 + 1] = c1;
  }
  float* bb = bkt + (size_t)(blk & 63) * 512;
  if (t < 64) atomicAdd(&bb[t], sSum[t]);
  else if (t < 128) atomicAdd(&bb[64 + (t - 64)], sSq[t - 64]);
}

// ---------------------------------------------------------------------------
// GEMM2 (MFMA bf16): bn1+relu(Y) -> conv2(64->64)+bias, Y bf16 IN-PLACE.
// ---------------------------------------------------------------------------
__global__ __launch_bounds__(256) void gemm2_mfma_kernel(u16* __restrict__ Y,
                                                         const float* __restrict__ w2,
                                                         const float* __restrict__ b2,
                                                         const float* __restrict__ g1,
                                                         const float* __restrict__ be1,
                                                         const float* __restrict__ statsC,
                                                         float* __restrict__ bkt) {
  __shared__ __align__(16) short Af[8 * 64 * 8];
  __shared__ __align__(16) short Bf[8 * 64 * 8];
  __shared__ __align__(16) u16 Cs[64 * 72];
  __shared__ float sS[64], sT[64];
  __shared__ float sSum[64], sSq[64];
  const int t = threadIdx.x, blk = blockIdx.x;
  const int pbase = blk * 64;
  if (t < 64) {
    float mean = statsC[t] * (1.0f / NT_F);
    float var = statsC[64 + t] * (1.0f / NT_F) - mean * mean;
    float s = g1[t] * rsqrtf(var + EPSV);
    sS[t] = s;
    sT[t] = be1[t] - mean * s;
  }
  __syncthreads();
  {
    int r = t >> 2, q = t & 3;
    const uint4* yrow = (const uint4*)(Y + (size_t)(pbase + r) * 64);
    union { uint4 u; u16 h[8]; } v0, v1;
    v0.u = yrow[q * 2]; v1.u = yrow[q * 2 + 1];
    int c0 = q * 16;
    int kt = c0 >> 5, mt = r >> 4;
    int qp0 = (c0 >> 3) & 3, qp1 = ((c0 + 8) >> 3) & 3;
    *(short8*)&Af[(((mt << 1) | kt) * 64 + qp0 * 16 + (r & 15)) * 8] = bn_pack8(v0.h, sS, sT, c0);
    *(short8*)&Af[(((mt << 1) | kt) * 64 + qp1 * 16 + (r & 15)) * 8] = bn_pack8(v1.h, sS, sT, c0 + 8);
  }
  {
    int o = t >> 2, q = t & 3;
    const float* wrow = w2 + o * 64 + q * 16;
    float f0[8], f1[8];
#pragma unroll
    for (int x = 0; x < 8; x++) { f0[x] = wrow[x]; f1[x] = wrow[8 + x]; }
    int c0 = q * 16;
    int kt = c0 >> 5, nt = o >> 4;
    int qp0 = (c0 >> 3) & 3, qp1 = ((c0 + 8) >> 3) & 3;
    *(short8*)&Bf[(((nt << 1) | kt) * 64 + qp0 * 16 + (o & 15)) * 8] = w_pack8(f0);
    *(short8*)&Bf[(((nt << 1) | kt) * 64 + qp1 * 16 + (o & 15)) * 8] = w_pack8(f1);
  }
  __syncthreads();
  const int w = t >> 6, L = t & 63, q = L >> 4;
  const int nt = w;
  short8 b0 = *(const short8*)&Bf[((nt * 2 + 0) * 64 + L) * 8];
  short8 b1 = *(const short8*)&Bf[((nt * 2 + 1) * 64 + L) * 8];
  const int o = nt * 16 + (L & 15);
  const float bl = b2[o];
  f32x4 acc[4];
#pragma unroll
  for (int mt = 0; mt < 4; mt++) {
    acc[mt] = (f32x4){0.f, 0.f, 0.f, 0.f};
    short8 a0 = *(const short8*)&Af[((mt * 2 + 0) * 64 + L) * 8];
    short8 a1 = *(const short8*)&Af[((mt * 2 + 1) * 64 + L) * 8];
    acc[mt] = __builtin_amdgcn_mfma_f32_16x16x32_bf16(a0, b0, acc[mt], 0, 0, 0);
    acc[mt] = __builtin_amdgcn_mfma_f32_16x16x32_bf16(a1, b1, acc[mt], 0, 0, 0);
  }
  float s = 0.f, q2 = 0.f;
#pragma unroll
  for (int mt = 0; mt < 4; mt++) {
    float yv[4];
#pragma unroll
    for (int r = 0; r < 4; r++) {
      yv[r] = acc[mt][r] + bl;
      s += yv[r]; q2 += yv[r] * yv[r];
    }
#pragma unroll
    for (int r = 0; r < 4; r += 2) {
      __hip_bfloat162 p = __float22bfloat162_rn(make_float2(yv[r], yv[r + 1]));
      unsigned u = *(const unsigned*)&p;
      Cs[(mt * 16 + q * 4 + r) * 72 + o] = (u16)(u & 0xFFFF);
      Cs[(mt * 16 + q * 4 + r + 1) * 72 + o] = (u16)(u >> 16);
    }
  }
  s += __shfl_xor(s, 16); s += __shfl_xor(s, 32);
  q2 += __shfl_xor(q2, 16); q2 += __shfl_xor(q2, 32);
  if (L < 16) { sSum[o] = s; sSq[o] = q2; }
  __syncthreads();
  {
    int r = t >> 2, qq = t & 3;
    uint4 c0 = *(const uint4*)&Cs[r * 72 + qq * 16];
    uint4 c1 = *(const uint4*)&Cs[r * 72 + qq * 16 + 8];
    uint4* yrow = (uint4*)(Y + (size_t)(pbase + r) * 64);
    yrow[qq * 2] = c0; yrow[qq * 2 + 1] = c1;
  }
  float* bb = bkt + (size_t)(blk & 63) * 512;
  if (t < 64) atomicAdd(&bb[128 + t], sSum[t]);
  else if (t < 128) atomicAdd(&bb[192 + (t - 64)], sSq[t - 64]);
}

// ---------------------------------------------------------------------------
// conv3max (MFMA bf16): bn2+relu(Y) -> conv3(64->128)+bias = y3;
// stats3 + per-(group,ch) max/min via shfl-reduce + unique-writer.
// ---------------------------------------------------------------------------
__global__ __launch_bounds__(256) void conv3max_mfma_kernel(const u16* __restrict__ Y,
                                                            const float* __restrict__ w3,
                                                            const float* __restrict__ b3,
                                                            const float* __restrict__ g2,
                                                            const float* __restrict__ be2,
                                                            const float* __restrict__ statsC,
                                                            float* __restrict__ bkt,
                                                            float* __restrict__ gmax,
                                                            float* __restrict__ gmin) {
  __shared__ __align__(16) short Af[8 * 64 * 8];
  __shared__ __align__(16) short Bf[16 * 64 * 8];
  __shared__ float sS[64], sT[64];
  __shared__ float sSum[128], sSq[128];
  const int t = threadIdx.x, blk = blockIdx.x;
  const int pbase = blk * 64;
  if (t < 64) {
    float mean = statsC[128 + t] * (1.0f / NT_F);
    float var = statsC[192 + t] * (1.0f / NT_F) - mean * mean;
    float s = g2[t] * rsqrtf(var + EPSV);
    sS[t] = s;
    sT[t] = be2[t] - mean * s;
  }
  __syncthreads();
  {
    int r = t >> 2, q = t & 3;
    const uint4* yrow = (const uint4*)(Y + (size_t)(pbase + r) * 64);
    union { uint4 u; u16 h[8]; } v0, v1;
    v0.u = yrow[q * 2]; v1.u = yrow[q * 2 + 1];
    int c0 = q * 16;
    int kt = c0 >> 5, mt = r >> 4;
    int qp0 = (c0 >> 3) & 3, qp1 = ((c0 + 8) >> 3) & 3;
    *(short8*)&Af[(((mt << 1) | kt) * 64 + qp0 * 16 + (r & 15)) * 8] = bn_pack8(v0.h, sS, sT, c0);
    *(short8*)&Af[(((mt << 1) | kt) * 64 + qp1 * 16 + (r & 15)) * 8] = bn_pack8(v1.h, sS, sT, c0 + 8);
  }
  {
    int o = t >> 1, h = t & 1;
    const float* wrow = w3 + o * 64 + h * 32;
    int nt = o >> 4;
#pragma unroll
    for (int g = 0; g < 4; g++) {
      float f[8];
#pragma unroll
      for (int x = 0; x < 8; x++) f[x] = wrow[g * 8 + x];
      *(short8*)&Bf[(((nt << 1) | h) * 64 + g * 16 + (o & 15)) * 8] = w_pack8(f);
    }
  }
  __syncthreads();
  const int w = t >> 6, L = t & 63, q = L >> 4;
  f32x4 acc[2][4];
#pragma unroll
  for (int n = 0; n < 2; n++)
#pragma unroll
    for (int mt = 0; mt < 4; mt++) acc[n][mt] = (f32x4){0.f, 0.f, 0.f, 0.f};
  short8 bfr[2][2];
#pragma unroll
  for (int n = 0; n < 2; n++) {
    int nt = 2 * w + n;
    bfr[n][0] = *(const short8*)&Bf[((nt * 2 + 0) * 64 + L) * 8];
    bfr[n][1] = *(const short8*)&Bf[((nt * 2 + 1) * 64 + L) * 8];
  }
#pragma unroll
  for (int mt = 0; mt < 4; mt++) {
    short8 a0 = *(const short8*)&Af[((mt * 2 + 0) * 64 + L) * 8];
    short8 a1 = *(const short8*)&Af[((mt * 2 + 1) * 64 + L) * 8];
#pragma unroll
    for (int n = 0; n < 2; n++) {
      acc[n][mt] = __builtin_amdgcn_mfma_f32_16x16x32_bf16(a0, bfr[n][0], acc[n][mt], 0, 0, 0);
      acc[n][mt] = __builtin_amdgcn_mfma_f32_16x16x32_bf16(a1, bfr[n][1], acc[n][mt], 0, 0, 0);
    }
  }
#pragma unroll
  for (int n = 0; n < 2; n++) {
    int o = (2 * w + n) * 16 + (L & 15);
    float bl = b3[o];
    float s = 0.f, q2 = 0.f;
    float gmx[2] = {-1e30f, -1e30f}, gmn[2] = {1e30f, 1e30f};
#pragma unroll
    for (int mt = 0; mt < 4; mt++) {
      int g = mt >> 1;
#pragma unroll
      for (int r = 0; r < 4; r++) {
        float y = acc[n][mt][r] + bl;
        s += y; q2 += y * y;
        gmx[g] = fmaxf(gmx[g], y);
        gmn[g] = fminf(gmn[g], y);
      }
    }
    s += __shfl_xor(s, 16); s += __shfl_xor(s, 32);
    q2 += __shfl_xor(q2, 16); q2 += __shfl_xor(q2, 32);
#pragma unroll
    for (int g = 0; g < 2; g++) {
      gmx[g] = fmaxf(gmx[g], __shfl_xor(gmx[g], 16));
      gmx[g] = fmaxf(gmx[g], __shfl_xor(gmx[g], 32));
      gmn[g] = fminf(gmn[g], __shfl_xor(gmn[g], 16));
      gmn[g] = fminf(gmn[g], __shfl_xor(gmn[g], 32));
    }
    if (L < 16) {
      sSum[o] = s; sSq[o] = q2;
#pragma unroll
      for (int g = 0; g < 2; g++) {
        gmax[(size_t)(blk * 2 + g) * 128 + o] = gmx[g];
        gmin[(size_t)(blk * 2 + g) * 128 + o] = gmn[g];
      }
    }
  }
  __syncthreads();
  float* bb = bkt + (size_t)(blk & 63) * 512;
  if (t < 128) atomicAdd(&bb[256 + t], sSum[t]);
  else atomicAdd(&bb[384 + (t - 128)], sSq[t - 128]);
}

// ---------------------------------------------------------------------------
// finalize (tiled): coalesced reads, LDS transpose, coalesced writes.
// ---------------------------------------------------------------------------
__global__ __launch_bounds__(256) void finalize_kernel(const float* __restrict__ gmax,
                                                       const float* __restrict__ gmin,
                                                       const float* __restrict__ statsC,
                                                       const float* __restrict__ g3,
                                                       const float* __restrict__ be3,
                                                       float* __restrict__ outf) {
  __shared__ float smax[64 * 65], smin[64 * 65];
  __shared__ float ssc[64], ssh[64];
  const int t = threadIdx.x, blk = blockIdx.x;
  const int b = blk >> 5, st = (blk >> 1) & 15, oh = blk & 1;
  const int o0 = oh * 64, g0 = b * 1024 + st * 64;
  if (t < 64) {
    int o = o0 + t;
    float mean = statsC[256 + o] * (1.0f / NT_F);
    float var = statsC[384 + o] * (1.0f / NT_F) - mean * mean;
    float sc = g3[o] * rsqrtf(var + EPSV);
    ssc[t] = sc;
    ssh[t] = be3[o] - mean * sc;
  }
  const int col = t & 63, rw = t >> 6;
#pragma unroll
  for (int k = 0; k < 16; k++) {
    int r = k * 4 + rw;
    smax[r * 65 + col] = gmax[(size_t)(g0 + r) * 128 + o0 + col];
    smin[r * 65 + col] = gmin[(size_t)(g0 + r) * 128 + o0 + col];
  }
  __syncthreads();
#pragma unroll
  for (int k = 0; k < 16; k++) {
    int o = k * 4 + rw;
    float sc = ssc[o], sh = ssh[o];
    float v = sc > 0.f ? smax[col * 65 + o] : smin[col * 65 + o];
    outf[((size_t)(b * 128 + o0 + o)) * 1024 + st * 64 + col] = fmaxf(fmaf(v, sc, sh), 0.f);
  }
}

// ---------------------------------------------------------------------------
// launch
// ---------------------------------------------------------------------------
extern "C" void kernel_launch(void* const* d_in, const int* in_sizes, int n_in,
                              void* d_out, int out_size, void* d_ws, size_t ws_size,
                              hipStream_t stream) {
  const float* xyz = (const float*)d_in[0];
  const float* pts = (const float*)d_in[1];
  const float* w1 = (const float*)d_in[2];
  const float* b1 = (const float*)d_in[3];
  const float* g1 = (const float*)d_in[4];
  const float* be1 = (const float*)d_in[5];
  const float* w2 = (const float*)d_in[6];
  const float* b2 = (const float*)d_in[7];
  const float* g2 = (const float*)d_in[8];
  const float* be2 = (const float*)d_in[9];
  const float* w3 = (const float*)d_in[10];
  const float* b3 = (const float*)d_in[11];
  const float* g3 = (const float*)d_in[12];
  const float* be3 = (const float*)d_in[13];

  float* out = (float*)d_out;
  float* newxyz = out;            // 16*1024*3
  float* outfeat = out + 49152;   // 16*128*1024

  char* ws = (char*)d_ws;
  int* ballidx = (int*)ws;                           // 2 MB
  float* bkt = (float*)(ws + (2 << 20));             // 128 KB
  float* statsC = (float*)(ws + (2 << 20) + 131072); // 2 KB
  float* gmax = (float*)(ws + (4 << 20));            // 8 MB
  float* gmin = (float*)(ws + (12 << 20));           // 8 MB
  u16* Y = (u16*)(ws + (20 << 20));                  // 64 MiB (in-place Y1->Y2)

  hipMemsetAsync(bkt, 0, 64 * 512 * sizeof(float), stream);

  bool use_bucket = false;
  {
    hipError_t e = hipFuncSetAttribute((const void*)fps_bucket_kernel,
                                       hipFuncAttributeMaxDynamicSharedMemorySize, 131072);
    if (e == hipSuccess) {
      int nb = 0;
      hipError_t e2 = hipOccupancyMaxActiveBlocksPerMultiprocessor(
          &nb, (const void*)fps_bucket_kernel, 1024, 131072);
      use_bucket = (e2 == hipSuccess && nb >= 1);
    }
  }
  if (use_bucket)
    fps_bucket_kernel<<<16, 1024, 131072, stream>>>(xyz, newxyz);
  else
    fps_fallback_kernel<<<16, 512, 0, stream>>>(xyz, newxyz);

  ballq_kernel<<<4096, 256, 0, stream>>>(xyz, newxyz, ballidx);
  gemm1_mfma_kernel<<<8192, 256, 0, stream>>>(xyz, pts, w1, b1, newxyz, ballidx, Y, bkt);
  collapse_kernel<<<2, 256, 0, stream>>>(bkt, statsC);
  gemm2_mfma_kernel<<<8192, 256, 0, stream>>>(Y, w2, b2, g1, be1, statsC, bkt);
  collapse_kernel<<<2, 256, 0, stream>>>(bkt, statsC);
  conv3max_mfma_kernel<<<8192, 256, 0, stream>>>(Y, w3, b3, g2, be2, statsC, bkt, gmax, gmin);
  collapse_kernel<<<2, 256, 0, stream>>>(bkt, statsC);
  finalize_kernel<<<512, 256, 0, stream>>>(gmax, gmin, statsC, g3, be3, outfeat);
}

// Round 9
// 1266.395 us; speedup vs baseline: 1.0031x; 1.0031x over previous
//
#include <hip/hip_runtime.h>
#include <hip/hip_bf16.h>

typedef unsigned short u16;
typedef unsigned long long u64;
typedef __attribute__((ext_vector_type(8))) short short8;
typedef __attribute__((ext_vector_type(4))) float f32x4;

#define NN 8192
#define SSAMP 1024
#define KK 32
#define NT_F 524288.0f
#define EPSV 1e-5f

__device__ __forceinline__ u64 umax64(u64 a, u64 b) { return a > b ? a : b; }

template <int C>
__device__ __forceinline__ void dppstep(unsigned& hi, unsigned& lo) {
  unsigned h2 = (unsigned)__builtin_amdgcn_update_dpp(0, (int)hi, C, 0xF, 0xF, true);
  unsigned l2 = (unsigned)__builtin_amdgcn_update_dpp(0, (int)lo, C, 0xF, 0xF, true);
  u64 a = ((u64)hi << 32) | lo;
  u64 b = ((u64)h2 << 32) | l2;
  bool g = b > a;
  hi = g ? h2 : hi;
  lo = g ? l2 : lo;
}

// Full wave64 max-reduce; valid result in lane 63.
__device__ __forceinline__ u64 wave_max_key(u64 key) {
  unsigned hi = (unsigned)(key >> 32), lo = (unsigned)key;
  dppstep<0x111>(hi, lo);
  dppstep<0x112>(hi, lo);
  dppstep<0x114>(hi, lo);
  dppstep<0x118>(hi, lo);
  dppstep<0x142>(hi, lo);
  dppstep<0x143>(hi, lo);
  return ((u64)hi << 32) | lo;
}

__device__ __forceinline__ int morton3(int ix, int iy, int iz) {
  int m = (((ix >> 0) & 1) << 2) | (((iy >> 0) & 1) << 1) | (((iz >> 0) & 1) << 0);
  m |= (((ix >> 1) & 1) << 5) | (((iy >> 1) & 1) << 4) | (((iz >> 1) & 1) << 3);
  m |= (((ix >> 2) & 1) << 8) | (((iy >> 2) & 1) << 7) | (((iz >> 2) & 1) << 6);
  return m;
}

// ---------------------------------------------------------------------------
// FPS (round-6 v6, best measured 722 us): bucketed + pruned, conditional wave
// reduce with per-wave cached reduced key, single LDS atomicMax slot with
// 3-buffer rotation (race-free with one barrier/iter). Key =
// (dist_bits<<26) | ((8191-orig)<<13) | sorted_pos. Distances bit-exact vs
// reference: (dx*dx + dy*dy) + dz*dz with rn ops; prune skips only when fmin
// is provably identity.
// ---------------------------------------------------------------------------
__global__ __launch_bounds__(1024, 1) void fps_bucket_kernel(const float* __restrict__ xyz,
                                                             float* __restrict__ newxyz) {
  extern __shared__ float dynls[];
  float* sx = dynls;                 // [NN]
  float* sy = dynls + NN;            // [NN]
  float* sz = dynls + 2 * NN;        // [NN]
  int* sI = (int*)(dynls + 3 * NN);  // [NN]
  __shared__ int cnt[512], off[512];
  __shared__ u64 candS[3];
  __shared__ int pos0_sh;

  const int b = blockIdx.x, t = threadIdx.x;
  const float* base = xyz + (size_t)b * NN * 3;

  float px[8], py[8], pz[8];
  int pc[8];
  if (t < 512) cnt[t] = 0;
  if (t == 0) { candS[0] = 0; candS[1] = 0; candS[2] = 0; }
  __syncthreads();
#pragma unroll
  for (int j = 0; j < 8; j++) {
    int p = j * 1024 + t;
    px[j] = base[p * 3 + 0];
    py[j] = base[p * 3 + 1];
    pz[j] = base[p * 3 + 2];
    int ix = min(7, (int)(px[j] * 8.0f));
    int iy = min(7, (int)(py[j] * 8.0f));
    int iz = min(7, (int)(pz[j] * 8.0f));
    pc[j] = morton3(ix, iy, iz);
    atomicAdd(&cnt[pc[j]], 1);
  }
  __syncthreads();
  int myc = (t < 512) ? cnt[t] : 0;
  for (int st = 1; st < 512; st <<= 1) {
    int v = 0;
    if (t < 512) { v = cnt[t]; if (t >= st) v += cnt[t - st]; }
    __syncthreads();
    if (t < 512) cnt[t] = v;
    __syncthreads();
  }
  if (t < 512) off[t] = cnt[t] - myc;
  __syncthreads();
#pragma unroll
  for (int j = 0; j < 8; j++) {
    int pos = atomicAdd(&off[pc[j]], 1);
    sx[pos] = px[j]; sy[pos] = py[j]; sz[pos] = pz[j];
    int orig = j * 1024 + t;
    sI[pos] = orig;
    if (orig == 0) pos0_sh = pos;
  }
  __syncthreads();
  float X[8], Y[8], Z[8], D[8];
  unsigned L26[8];
  float lox = 1e30f, loy = 1e30f, loz = 1e30f;
  float hix = -1e30f, hiy = -1e30f, hiz = -1e30f;
#pragma unroll
  for (int j = 0; j < 8; j++) {
    int p = t * 8 + j;
    float x = sx[p], y = sy[p], z = sz[p];
    X[j] = x; Y[j] = y; Z[j] = z; D[j] = 1e10f;
    int orig = sI[p];
    L26[j] = ((unsigned)(8191 - orig) << 13) | (unsigned)p;
    lox = fminf(lox, x); hix = fmaxf(hix, x);
    loy = fminf(loy, y); hiy = fmaxf(hiy, y);
    loz = fminf(loz, z); hiz = fmaxf(hiz, z);
  }
  int cur = pos0_sh;
  u64 ckey = 0;       // per-lane cached argmax key
  float cbd = 1e30f;  // per-lane cached max residual distance
  u64 wkeyS = 0;      // lane63 holds this wave's reduced key
  int s = 0;

  for (int it = 0; it < SSAMP; it++) {
    const int sn = (s == 2) ? 0 : s + 1;
    float cx = sx[cur], cy = sy[cur], cz = sz[cur];
    if (t == 0) {
      float* o = newxyz + ((size_t)b * SSAMP + it) * 3;
      o[0] = cx; o[1] = cy; o[2] = cz;
    }
    float ddx = fmaxf(fmaxf(lox - cx, cx - hix), 0.f);
    float ddy = fmaxf(fmaxf(loy - cy, cy - hiy), 0.f);
    float ddz = fmaxf(fmaxf(loz - cz, cz - hiz), 0.f);
    float lb2 = fmaf(ddx, ddx, fmaf(ddy, ddy, ddz * ddz));
    bool upd = lb2 <= fmaf(cbd, 1.0001f, 1e-12f);
    if (__ballot(upd)) {  // wave-uniform branch
      if (upd) {
        u64 k = 0;
        float bd = -1.0f;
#pragma unroll
        for (int j = 0; j < 8; j++) {
          float dx = __fsub_rn(X[j], cx);
          float dy = __fsub_rn(Y[j], cy);
          float dz = __fsub_rn(Z[j], cz);
          float d = __fadd_rn(__fadd_rn(__fmul_rn(dx, dx), __fmul_rn(dy, dy)), __fmul_rn(dz, dz));
          float dm = fminf(D[j], d);
          D[j] = dm;
          bd = fmaxf(bd, dm);
          u64 kj = ((u64)__float_as_uint(dm) << 26) | (u64)L26[j];
          k = umax64(k, kj);
        }
        ckey = k;
        cbd = bd;
      }
      wkeyS = wave_max_key(ckey);  // lane63 valid
    }
    if ((t & 63) == 63) atomicMax(&candS[s], wkeyS);
    if (t == 0) candS[sn] = 0;  // race-free per 3-buffer rotation
    __syncthreads();
    cur = (int)(candS[s] & 0x1FFFull);
    s = sn;
  }
}

// ---------------------------------------------------------------------------
// FPS fallback (global loads) if big-LDS launch isn't grantable.
// ---------------------------------------------------------------------------
__global__ __launch_bounds__(512, 1) void fps_fallback_kernel(const float* __restrict__ xyz,
                                                              float* __restrict__ newxyz) {
  const int b = blockIdx.x, t = threadIdx.x;
  const float* base = xyz + (size_t)b * NN * 3;
  __shared__ u64 cand[2][8];
  float X[16], Y[16], Z[16], D[16];
#pragma unroll
  for (int j = 0; j < 16; j++) {
    int p = j * 512 + t;
    X[j] = base[p * 3 + 0];
    Y[j] = base[p * 3 + 1];
    Z[j] = base[p * 3 + 2];
    D[j] = 1e10f;
  }
  __syncthreads();
  int cur = 0;
  const int w = t >> 6;
  for (int it = 0; it < SSAMP; it++) {
    float cx = base[cur * 3 + 0];
    float cy = base[cur * 3 + 1];
    float cz = base[cur * 3 + 2];
    if (t == 0) {
      float* o = newxyz + ((size_t)b * SSAMP + it) * 3;
      o[0] = cx; o[1] = cy; o[2] = cz;
    }
    float bestd = -1.0f;
    int bj = 0;
#pragma unroll
    for (int j = 0; j < 16; j++) {
      float dx = __fsub_rn(X[j], cx);
      float dy = __fsub_rn(Y[j], cy);
      float dz = __fsub_rn(Z[j], cz);
      float d = __fadd_rn(__fadd_rn(__fmul_rn(dx, dx), __fmul_rn(dy, dy)), __fmul_rn(dz, dz));
      float dm = fminf(D[j], d);
      D[j] = dm;
      bool g = dm > bestd;
      bestd = g ? dm : bestd;
      bj = g ? j : bj;
    }
    u64 key = ((u64)__float_as_uint(bestd) << 32) |
              (u64)(unsigned)~(unsigned)(bj * 512 + t);
    key = wave_max_key(key);
    const int s = it & 1;
    if ((t & 63) == 63) cand[s][w] = key;
    __syncthreads();
    u64 c0 = cand[s][0], c1 = cand[s][1], c2 = cand[s][2], c3 = cand[s][3];
    u64 c4 = cand[s][4], c5 = cand[s][5], c6 = cand[s][6], c7 = cand[s][7];
    u64 a0 = umax64(c0, c1), a1 = umax64(c2, c3), a2 = umax64(c4, c5), a3 = umax64(c6, c7);
    u64 best = umax64(umax64(a0, a1), umax64(a2, a3));
    cur = (int)(~(unsigned)(best & 0xFFFFFFFFull));
  }
}

// ---------------------------------------------------------------------------
// Ball query: one WAVE per centroid, 64-pt chunks, ballot + rank compaction.
// ---------------------------------------------------------------------------
__global__ __launch_bounds__(256) void ballq_kernel(const float* __restrict__ xyz,
                                                    const float* __restrict__ newxyz,
                                                    int* __restrict__ ballidx) {
  const int wid = blockIdx.x * 4 + (threadIdx.x >> 6);
  const int lane = threadIdx.x & 63;
  const int b = wid >> 10;
  const float* base = xyz + (size_t)b * NN * 3;
  const float cx = newxyz[wid * 3 + 0];
  const float cy = newxyz[wid * 3 + 1];
  const float cz = newxyz[wid * 3 + 2];
  int* op = ballidx + (size_t)wid * KK;
  int cnt = 0, first = -1;
  for (int p0 = 0; p0 < NN; p0 += 64) {
    const int p = p0 + lane;
    float dx = __fsub_rn(cx, base[p * 3 + 0]);
    float dy = __fsub_rn(cy, base[p * 3 + 1]);
    float dz = __fsub_rn(cz, base[p * 3 + 2]);
    float d = __fadd_rn(__fadd_rn(__fmul_rn(dx, dx), __fmul_rn(dy, dy)), __fmul_rn(dz, dz));
    bool hit = d <= 0.04f;
    u64 m = __ballot(hit);
    if (m) {
      if (first < 0) first = p0 + __ffsll((long long)m) - 1;
      int rank = __popcll(m & ((1ull << lane) - 1ull));
      int slot = cnt + rank;
      if (hit && slot < KK) op[slot] = p;
      cnt += __popcll(m);
      if (cnt >= KK) break;
    }
  }
  if (cnt < KK && lane >= cnt && lane < KK) op[lane] = first;
}

__global__ __launch_bounds__(256) void collapse_kernel(const float* __restrict__ bkt,
                                                       float* __restrict__ dst) {
  int e = blockIdx.x * 256 + threadIdx.x;
  float s = 0.f;
#pragma unroll 8
  for (int u = 0; u < 64; u++) s += bkt[u * 512 + e];
  dst[e] = s;
}

// pack helpers (packed bf16 converts)
__device__ __forceinline__ void put2(short8& r, int x, float f0, float f1) {
  __hip_bfloat162 p = __float22bfloat162_rn(make_float2(f0, f1));
  unsigned u = *(const unsigned*)&p;
  r[x] = (short)(u16)(u & 0xFFFF);
  r[x + 1] = (short)(u16)(u >> 16);
}

__device__ __forceinline__ short8 bn_pack8(const u16 h[8], const float* sS, const float* sT, int c0) {
  short8 r;
#pragma unroll
  for (int x = 0; x < 8; x += 2) {
    float f0 = __bfloat162float(*(const __hip_bfloat16*)&h[x]);
    float f1 = __bfloat162float(*(const __hip_bfloat16*)&h[x + 1]);
    f0 = fmaxf(fmaf(f0, sS[c0 + x], sT[c0 + x]), 0.f);
    f1 = fmaxf(fmaf(f1, sS[c0 + x + 1], sT[c0 + x + 1]), 0.f);
    put2(r, x, f0, f1);
  }
  return r;
}

__device__ __forceinline__ short8 w_pack8(const float v[8]) {
  short8 r;
#pragma unroll
  for (int x = 0; x < 8; x += 2) put2(r, x, v[x], v[x + 1]);
  return r;
}

// ---------------------------------------------------------------------------
// GEMM1 (MFMA bf16): gather(points, xyz_norm) -> conv1(67->64)+bias, Y bf16.
// K reorder: k0..63 = point ch 3..66, k64..66 = xyz_norm, rest zero.
// ---------------------------------------------------------------------------
__global__ __launch_bounds__(256) void gemm1_mfma_kernel(const float* __restrict__ xyz,
                                                         const float* __restrict__ pts,
                                                         const float* __restrict__ w1,
                                                         const float* __restrict__ b1,
                                                         const float* __restrict__ newxyz,
                                                         const int* __restrict__ ballidx,
                                                         u16* __restrict__ Y,
                                                         float* __restrict__ bkt) {
  __shared__ __align__(16) short Af[12 * 64 * 8];
  __shared__ __align__(16) short Bf[12 * 64 * 8];
  __shared__ __align__(16) u16 Cs[64 * 72];
  __shared__ int sidx[64];
  __shared__ float snx[6];
  __shared__ float sSum[64], sSq[64];
  const int t = threadIdx.x, blk = blockIdx.x;
  const int pbase = blk * 64;
  const int g0 = pbase >> 5;
  const int b = g0 >> 10;
  if (t < 64) sidx[t] = ballidx[pbase + t];
  if (t < 6) snx[t] = newxyz[(size_t)g0 * 3 + t];
  __syncthreads();
  {
    int r = t >> 2, q = t & 3;
    const float4* prow = (const float4*)(pts + ((size_t)b * NN + sidx[r]) * 64);
    float4 v0 = prow[q * 4 + 0], v1 = prow[q * 4 + 1];
    float4 v2 = prow[q * 4 + 2], v3 = prow[q * 4 + 3];
    float f0[8] = {v0.x, v0.y, v0.z, v0.w, v1.x, v1.y, v1.z, v1.w};
    float f1[8] = {v2.x, v2.y, v2.z, v2.w, v3.x, v3.y, v3.z, v3.w};
    int kt = q >> 1, mt = r >> 4, m = r & 15;
    int qp0 = (2 * q) & 3, qp1 = (2 * q + 1) & 3;
    *(short8*)&Af[((mt * 3 + kt) * 64 + qp0 * 16 + m) * 8] = w_pack8(f0);
    *(short8*)&Af[((mt * 3 + kt) * 64 + qp1 * 16 + m) * 8] = w_pack8(f1);
  }
  {
    int o = t >> 2, q = t & 3;
    const float* wr = w1 + o * 67 + 3 + q * 16;
    float f0[8], f1[8];
#pragma unroll
    for (int x = 0; x < 8; x++) { f0[x] = wr[x]; f1[x] = wr[8 + x]; }
    int kt = q >> 1, nt = o >> 4, n = o & 15;
    int qp0 = (2 * q) & 3, qp1 = (2 * q + 1) & 3;
    *(short8*)&Bf[((nt * 3 + kt) * 64 + qp0 * 16 + n) * 8] = w_pack8(f0);
    *(short8*)&Bf[((nt * 3 + kt) * 64 + qp1 * 16 + n) * 8] = w_pack8(f1);
  }
  if (t < 64) {
    const float* xp = xyz + ((size_t)b * NN + sidx[t]) * 3;
    int g = t >> 5, mt = t >> 4, m = t & 15;
    float xn = xp[0] - snx[g * 3 + 0];
    float yn = xp[1] - snx[g * 3 + 1];
    float zn = xp[2] - snx[g * 3 + 2];
    short8 s0 = {0, 0, 0, 0, 0, 0, 0, 0};
    short8 z8 = {0, 0, 0, 0, 0, 0, 0, 0};
    __hip_bfloat16 hb;
    hb = __float2bfloat16(xn); s0[0] = *(const short*)&hb;
    hb = __float2bfloat16(yn); s0[1] = *(const short*)&hb;
    hb = __float2bfloat16(zn); s0[2] = *(const short*)&hb;
    *(short8*)&Af[((mt * 3 + 2) * 64 + 0 * 16 + m) * 8] = s0;
    *(short8*)&Af[((mt * 3 + 2) * 64 + 1 * 16 + m) * 8] = z8;
    *(short8*)&Af[((mt * 3 + 2) * 64 + 2 * 16 + m) * 8] = z8;
    *(short8*)&Af[((mt * 3 + 2) * 64 + 3 * 16 + m) * 8] = z8;
  } else if (t < 128) {
    int o = t - 64, nt = o >> 4, n = o & 15;
    short8 s0 = {0, 0, 0, 0, 0, 0, 0, 0};
    short8 z8 = {0, 0, 0, 0, 0, 0, 0, 0};
    __hip_bfloat16 hb;
    hb = __float2bfloat16(w1[o * 67 + 0]); s0[0] = *(const short*)&hb;
    hb = __float2bfloat16(w1[o * 67 + 1]); s0[1] = *(const short*)&hb;
    hb = __float2bfloat16(w1[o * 67 + 2]); s0[2] = *(const short*)&hb;
    *(short8*)&Bf[((nt * 3 + 2) * 64 + 0 * 16 + n) * 8] = s0;
    *(short8*)&Bf[((nt * 3 + 2) * 64 + 1 * 16 + n) * 8] = z8;
    *(short8*)&Bf[((nt * 3 + 2) * 64 + 2 * 16 + n) * 8] = z8;
    *(short8*)&Bf[((nt * 3 + 2) * 64 + 3 * 16 + n) * 8] = z8;
  }
  __syncthreads();
  const int w = t >> 6, L = t & 63, q = L >> 4;
  const int nt = w;
  short8 b0 = *(const short8*)&Bf[((nt * 3 + 0) * 64 + L) * 8];
  short8 b1v = *(const short8*)&Bf[((nt * 3 + 1) * 64 + L) * 8];
  short8 b2v = *(const short8*)&Bf[((nt * 3 + 2) * 64 + L) * 8];
  const int o = nt * 16 + (L & 15);
  const float bl = b1[o];
  f32x4 acc[4];
#pragma unroll
  for (int mt = 0; mt < 4; mt++) {
    acc[mt] = (f32x4){0.f, 0.f, 0.f, 0.f};
    short8 a0 = *(const short8*)&Af[((mt * 3 + 0) * 64 + L) * 8];
    short8 a1 = *(const short8*)&Af[((mt * 3 + 1) * 64 + L) * 8];
    short8 a2 = *(const short8*)&Af[((mt * 3 + 2) * 64 + L) * 8];
    acc[mt] = __builtin_amdgcn_mfma_f32_16x16x32_bf16(a0, b0, acc[mt], 0, 0, 0);
    acc[mt] = __builtin_amdgcn_mfma_f32_16x16x32_bf16(a1, b1v, acc[mt], 0, 0, 0);
    acc[mt] = __builtin_amdgcn_mfma_f32_16x16x32_bf16(a2, b2v, acc[mt], 0, 0, 0);
  }
  float s = 0.f, q2 = 0.f;
#pragma unroll
  for (int mt = 0; mt < 4; mt++) {
    float yv[4];
#pragma unroll
    for (int r = 0; r < 4; r++) {
      yv[r] = acc[mt][r] + bl;
      s += yv[r]; q2 += yv[r] * yv[r];
    }
#pragma unroll
    for (int r = 0; r < 4; r += 2) {
      __hip_bfloat162 p = __float22bfloat162_rn(make_float2(yv[r], yv[r + 1]));
      unsigned u = *(const unsigned*)&p;
      Cs[(mt * 16 + q * 4 + r) * 72 + o] = (u16)(u & 0xFFFF);
      Cs[(mt * 16 + q * 4 + r + 1) * 72 + o] = (u16)(u >> 16);
    }
  }
  s += __shfl_xor(s, 16); s += __shfl_xor(s, 32);
  q2 += __shfl_xor(q2, 16); q2 += __shfl_xor(q2, 32);
  if (L < 16) { sSum[o] = s; sSq[o] = q2; }
  __syncthreads();
  {
    int r = t >> 2, qq = t & 3;
    uint4 c0 = *(const uint4*)&Cs[r * 72 + qq * 16];
    uint4 c1 = *(const uint4*)&Cs[r * 72 + qq * 16 + 8];
    uint4* yrow = (uint4*)(Y + (size_t)(pbase + r) * 64);
    yrow[qq * 2] = c0; yrow[qq * 2 + 1] = c1;
  }
  float* bb = bkt + (size_t)(blk & 63) * 512;
  if (t < 64) atomicAdd(&bb[t], sSum[t]);
  else if (t < 128) atomicAdd(&bb[64 + (t - 64)], sSq[t - 64]);
}

// ---------------------------------------------------------------------------
// GEMM2 (MFMA bf16): bn1+relu(Y) -> conv2(64->64)+bias, Y bf16 IN-PLACE.
// ---------------------------------------------------------------------------
__global__ __launch_bounds__(256) void gemm2_mfma_kernel(u16* __restrict__ Y,
                                                         const float* __restrict__ w2,
                                                         const float* __restrict__ b2,
                                                         const float* __restrict__ g1,
                                                         const float* __restrict__ be1,
                                                         const float* __restrict__ statsC,
                                                         float* __restrict__ bkt) {
  __shared__ __align__(16) short Af[8 * 64 * 8];
  __shared__ __align__(16) short Bf[8 * 64 * 8];
  __shared__ __align__(16) u16 Cs[64 * 72];
  __shared__ float sS[64], sT[64];
  __shared__ float sSum[64], sSq[64];
  const int t = threadIdx.x, blk = blockIdx.x;
  const int pbase = blk * 64;
  if (t < 64) {
    float mean = statsC[t] * (1.0f / NT_F);
    float var = statsC[64 + t] * (1.0f / NT_F) - mean * mean;
    float s = g1[t] * rsqrtf(var + EPSV);
    sS[t] = s;
    sT[t] = be1[t] - mean * s;
  }
  __syncthreads();
  {
    int r = t >> 2, q = t & 3;
    const uint4* yrow = (const uint4*)(Y + (size_t)(pbase + r) * 64);
    union { uint4 u; u16 h[8]; } v0, v1;
    v0.u = yrow[q * 2]; v1.u = yrow[q * 2 + 1];
    int c0 = q * 16;
    int kt = c0 >> 5, mt = r >> 4;
    int qp0 = (c0 >> 3) & 3, qp1 = ((c0 + 8) >> 3) & 3;
    *(short8*)&Af[(((mt << 1) | kt) * 64 + qp0 * 16 + (r & 15)) * 8] = bn_pack8(v0.h, sS, sT, c0);
    *(short8*)&Af[(((mt << 1) | kt) * 64 + qp1 * 16 + (r & 15)) * 8] = bn_pack8(v1.h, sS, sT, c0 + 8);
  }
  {
    int o = t >> 2, q = t & 3;
    const float* wrow = w2 + o * 64 + q * 16;
    float f0[8], f1[8];
#pragma unroll
    for (int x = 0; x < 8; x++) { f0[x] = wrow[x]; f1[x] = wrow[8 + x]; }
    int c0 = q * 16;
    int kt = c0 >> 5, nt = o >> 4;
    int qp0 = (c0 >> 3) & 3, qp1 = ((c0 + 8) >> 3) & 3;
    *(short8*)&Bf[(((nt << 1) | kt) * 64 + qp0 * 16 + (o & 15)) * 8] = w_pack8(f0);
    *(short8*)&Bf[(((nt << 1) | kt) * 64 + qp1 * 16 + (o & 15)) * 8] = w_pack8(f1);
  }
  __syncthreads();
  const int w = t >> 6, L = t & 63, q = L >> 4;
  const int nt = w;
  short8 b0 = *(const short8*)&Bf[((nt * 2 + 0) * 64 + L) * 8];
  short8 b1 = *(const short8*)&Bf[((nt * 2 + 1) * 64 + L) * 8];
  const int o = nt * 16 + (L & 15);
  const float bl = b2[o];
  f32x4 acc[4];
#pragma unroll
  for (int mt = 0; mt < 4; mt++) {
    acc[mt] = (f32x4){0.f, 0.f, 0.f, 0.f};
    short8 a0 = *(const short8*)&Af[((mt * 2 + 0) * 64 + L) * 8];
    short8 a1 = *(const short8*)&Af[((mt * 2 + 1) * 64 + L) * 8];
    acc[mt] = __builtin_amdgcn_mfma_f32_16x16x32_bf16(a0, b0, acc[mt], 0, 0, 0);
    acc[mt] = __builtin_amdgcn_mfma_f32_16x16x32_bf16(a1, b1, acc[mt], 0, 0, 0);
  }
  float s = 0.f, q2 = 0.f;
#pragma unroll
  for (int mt = 0; mt < 4; mt++) {
    float yv[4];
#pragma unroll
    for (int r = 0; r < 4; r++) {
      yv[r] = acc[mt][r] + bl;
      s += yv[r]; q2 += yv[r] * yv[r];
    }
#pragma unroll
    for (int r = 0; r < 4; r += 2) {
      __hip_bfloat162 p = __float22bfloat162_rn(make_float2(yv[r], yv[r + 1]));
      unsigned u = *(const unsigned*)&p;
      Cs[(mt * 16 + q * 4 + r) * 72 + o] = (u16)(u & 0xFFFF);
      Cs[(mt * 16 + q * 4 + r + 1) * 72 + o] = (u16)(u >> 16);
    }
  }
  s += __shfl_xor(s, 16); s += __shfl_xor(s, 32);
  q2 += __shfl_xor(q2, 16); q2 += __shfl_xor(q2, 32);
  if (L < 16) { sSum[o] = s; sSq[o] = q2; }
  __syncthreads();
  {
    int r = t >> 2, qq = t & 3;
    uint4 c0 = *(const uint4*)&Cs[r * 72 + qq * 16];
    uint4 c1 = *(const uint4*)&Cs[r * 72 + qq * 16 + 8];
    uint4* yrow = (uint4*)(Y + (size_t)(pbase + r) * 64);
    yrow[qq * 2] = c0; yrow[qq * 2 + 1] = c1;
  }
  float* bb = bkt + (size_t)(blk & 63) * 512;
  if (t < 64) atomicAdd(&bb[128 + t], sSum[t]);
  else if (t < 128) atomicAdd(&bb[192 + (t - 64)], sSq[t - 64]);
}

// ---------------------------------------------------------------------------
// conv3max (MFMA bf16): bn2+relu(Y) -> conv3(64->128)+bias = y3;
// stats3 + per-(group,ch) max/min via shfl-reduce + unique-writer.
// ---------------------------------------------------------------------------
__global__ __launch_bounds__(256) void conv3max_mfma_kernel(const u16* __restrict__ Y,
                                                            const float* __restrict__ w3,
                                                            const float* __restrict__ b3,
                                                            const float* __restrict__ g2,
                                                            const float* __restrict__ be2,
                                                            const float* __restrict__ statsC,
                                                            float* __restrict__ bkt,
                                                            float* __restrict__ gmax,
                                                            float* __restrict__ gmin) {
  __shared__ __align__(16) short Af[8 * 64 * 8];
  __shared__ __align__(16) short Bf[16 * 64 * 8];
  __shared__ float sS[64], sT[64];
  __shared__ float sSum[128], sSq[128];
  const int t = threadIdx.x, blk = blockIdx.x;
  const int pbase = blk * 64;
  if (t < 64) {
    float mean = statsC[128 + t] * (1.0f / NT_F);
    float var = statsC[192 + t] * (1.0f / NT_F) - mean * mean;
    float s = g2[t] * rsqrtf(var + EPSV);
    sS[t] = s;
    sT[t] = be2[t] - mean * s;
  }
  __syncthreads();
  {
    int r = t >> 2, q = t & 3;
    const uint4* yrow = (const uint4*)(Y + (size_t)(pbase + r) * 64);
    union { uint4 u; u16 h[8]; } v0, v1;
    v0.u = yrow[q * 2]; v1.u = yrow[q * 2 + 1];
    int c0 = q * 16;
    int kt = c0 >> 5, mt = r >> 4;
    int qp0 = (c0 >> 3) & 3, qp1 = ((c0 + 8) >> 3) & 3;
    *(short8*)&Af[(((mt << 1) | kt) * 64 + qp0 * 16 + (r & 15)) * 8] = bn_pack8(v0.h, sS, sT, c0);
    *(short8*)&Af[(((mt << 1) | kt) * 64 + qp1 * 16 + (r & 15)) * 8] = bn_pack8(v1.h, sS, sT, c0 + 8);
  }
  {
    int o = t >> 1, h = t & 1;
    const float* wrow = w3 + o * 64 + h * 32;
    int nt = o >> 4;
#pragma unroll
    for (int g = 0; g < 4; g++) {
      float f[8];
#pragma unroll
      for (int x = 0; x < 8; x++) f[x] = wrow[g * 8 + x];
      *(short8*)&Bf[(((nt << 1) | h) * 64 + g * 16 + (o & 15)) * 8] = w_pack8(f);
    }
  }
  __syncthreads();
  const int w = t >> 6, L = t & 63, q = L >> 4;
  f32x4 acc[2][4];
#pragma unroll
  for (int n = 0; n < 2; n++)
#pragma unroll
    for (int mt = 0; mt < 4; mt++) acc[n][mt] = (f32x4){0.f, 0.f, 0.f, 0.f};
  short8 bfr[2][2];
#pragma unroll
  for (int n = 0; n < 2; n++) {
    int nt = 2 * w + n;
    bfr[n][0] = *(const short8*)&Bf[((nt * 2 + 0) * 64 + L) * 8];
    bfr[n][1] = *(const short8*)&Bf[((nt * 2 + 1) * 64 + L) * 8];
  }
#pragma unroll
  for (int mt = 0; mt < 4; mt++) {
    short8 a0 = *(const short8*)&Af[((mt * 2 + 0) * 64 + L) * 8];
    short8 a1 = *(const short8*)&Af[((mt * 2 + 1) * 64 + L) * 8];
#pragma unroll
    for (int n = 0; n < 2; n++) {
      acc[n][mt] = __builtin_amdgcn_mfma_f32_16x16x32_bf16(a0, bfr[n][0], acc[n][mt], 0, 0, 0);
      acc[n][mt] = __builtin_amdgcn_mfma_f32_16x16x32_bf16(a1, bfr[n][1], acc[n][mt], 0, 0, 0);
    }
  }
#pragma unroll
  for (int n = 0; n < 2; n++) {
    int o = (2 * w + n) * 16 + (L & 15);
    float bl = b3[o];
    float s = 0.f, q2 = 0.f;
    float gmx[2] = {-1e30f, -1e30f}, gmn[2] = {1e30f, 1e30f};
#pragma unroll
    for (int mt = 0; mt < 4; mt++) {
      int g = mt >> 1;
#pragma unroll
      for (int r = 0; r < 4; r++) {
        float y = acc[n][mt][r] + bl;
        s += y; q2 += y * y;
        gmx[g] = fmaxf(gmx[g], y);
        gmn[g] = fminf(gmn[g], y);
      }
    }
    s += __shfl_xor(s, 16); s += __shfl_xor(s, 32);
    q2 += __shfl_xor(q2, 16); q2 += __shfl_xor(q2, 32);
#pragma unroll
    for (int g = 0; g < 2; g++) {
      gmx[g] = fmaxf(gmx[g], __shfl_xor(gmx[g], 16));
      gmx[g] = fmaxf(gmx[g], __shfl_xor(gmx[g], 32));
      gmn[g] = fminf(gmn[g], __shfl_xor(gmn[g], 16));
      gmn[g] = fminf(gmn[g], __shfl_xor(gmn[g], 32));
    }
    if (L < 16) {
      sSum[o] = s; sSq[o] = q2;
#pragma unroll
      for (int g = 0; g < 2; g++) {
        gmax[(size_t)(blk * 2 + g) * 128 + o] = gmx[g];
        gmin[(size_t)(blk * 2 + g) * 128 + o] = gmn[g];
      }
    }
  }
  __syncthreads();
  float* bb = bkt + (size_t)(blk & 63) * 512;
  if (t < 128) atomicAdd(&bb[256 + t], sSum[t]);
  else atomicAdd(&bb[384 + (t - 128)], sSq[t - 128]);
}

// ---------------------------------------------------------------------------
// finalize (tiled): coalesced reads, LDS transpose, coalesced writes.
// ---------------------------------------------------------------------------
__global__ __launch_bounds__(256) void finalize_kernel(const float* __restrict__ gmax,
                                                       const float* __restrict__ gmin,
                                                       const float* __restrict__ statsC,
                                                       const float* __restrict__ g3,
                                                       const float* __restrict__ be3,
                                                       float* __restrict__ outf) {
  __shared__ float smax[64 * 65], smin[64 * 65];
  __shared__ float ssc[64], ssh[64];
  const int t = threadIdx.x, blk = blockIdx.x;
  const int b = blk >> 5, st = (blk >> 1) & 15, oh = blk & 1;
  const int o0 = oh * 64, g0 = b * 1024 + st * 64;
  if (t < 64) {
    int o = o0 + t;
    float mean = statsC[256 + o] * (1.0f / NT_F);
    float var = statsC[384 + o] * (1.0f / NT_F) - mean * mean;
    float sc = g3[o] * rsqrtf(var + EPSV);
    ssc[t] = sc;
    ssh[t] = be3[o] - mean * sc;
  }
  const int col = t & 63, rw = t >> 6;
#pragma unroll
  for (int k = 0; k < 16; k++) {
    int r = k * 4 + rw;
    smax[r * 65 + col] = gmax[(size_t)(g0 + r) * 128 + o0 + col];
    smin[r * 65 + col] = gmin[(size_t)(g0 + r) * 128 + o0 + col];
  }
  __syncthreads();
#pragma unroll
  for (int k = 0; k < 16; k++) {
    int o = k * 4 + rw;
    float sc = ssc[o], sh = ssh[o];
    float v = sc > 0.f ? smax[col * 65 + o] : smin[col * 65 + o];
    outf[((size_t)(b * 128 + o0 + o)) * 1024 + st * 64 + col] = fmaxf(fmaf(v, sc, sh), 0.f);
  }
}

// ---------------------------------------------------------------------------
// launch
// ---------------------------------------------------------------------------
extern "C" void kernel_launch(void* const* d_in, const int* in_sizes, int n_in,
                              void* d_out, int out_size, void* d_ws, size_t ws_size,
                              hipStream_t stream) {
  const float* xyz = (const float*)d_in[0];
  const float* pts = (const float*)d_in[1];
  const float* w1 = (const float*)d_in[2];
  const float* b1 = (const float*)d_in[3];
  const float* g1 = (const float*)d_in[4];
  const float* be1 = (const float*)d_in[5];
  const float* w2 = (const float*)d_in[6];
  const float* b2 = (const float*)d_in[7];
  const float* g2 = (const float*)d_in[8];
  const float* be2 = (const float*)d_in[9];
  const float* w3 = (const float*)d_in[10];
  const float* b3 = (const float*)d_in[11];
  const float* g3 = (const float*)d_in[12];
  const float* be3 = (const float*)d_in[13];

  float* out = (float*)d_out;
  float* newxyz = out;            // 16*1024*3
  float* outfeat = out + 49152;   // 16*128*1024

  char* ws = (char*)d_ws;
  int* ballidx = (int*)ws;                           // 2 MB
  float* bkt = (float*)(ws + (2 << 20));             // 128 KB
  float* statsC = (float*)(ws + (2 << 20) + 131072); // 2 KB
  float* gmax = (float*)(ws + (4 << 20));            // 8 MB
  float* gmin = (float*)(ws + (12 << 20));           // 8 MB
  u16* Y = (u16*)(ws + (20 << 20));                  // 64 MiB (in-place Y1->Y2)

  hipMemsetAsync(bkt, 0, 64 * 512 * sizeof(float), stream);

  bool use_bucket = false;
  {
    hipError_t e = hipFuncSetAttribute((const void*)fps_bucket_kernel,
                                       hipFuncAttributeMaxDynamicSharedMemorySize, 131072);
    if (e == hipSuccess) {
      int nb = 0;
      hipError_t e2 = hipOccupancyMaxActiveBlocksPerMultiprocessor(
          &nb, (const void*)fps_bucket_kernel, 1024, 131072);
      use_bucket = (e2 == hipSuccess && nb >= 1);
    }
  }
  if (use_bucket)
    fps_bucket_kernel<<<16, 1024, 131072, stream>>>(xyz, newxyz);
  else
    fps_fallback_kernel<<<16, 512, 0, stream>>>(xyz, newxyz);

  ballq_kernel<<<4096, 256, 0, stream>>>(xyz, newxyz, ballidx);
  gemm1_mfma_kernel<<<8192, 256, 0, stream>>>(xyz, pts, w1, b1, newxyz, ballidx, Y, bkt);
  collapse_kernel<<<2, 256, 0, stream>>>(bkt, statsC);
  gemm2_mfma_kernel<<<8192, 256, 0, stream>>>(Y, w2, b2, g1, be1, statsC, bkt);
  collapse_kernel<<<2, 256, 0, stream>>>(bkt, statsC);
  conv3max_mfma_kernel<<<8192, 256, 0, stream>>>(Y, w3, b3, g2, be2, statsC, bkt, gmax, gmin);
  collapse_kernel<<<2, 256, 0, stream>>>(bkt, statsC);
  finalize_kernel<<<512, 256, 0, stream>>>(gmax, gmin, statsC, g3, be3, outfeat);
}